// Round 2
// baseline (610.864 us; speedup 1.0000x reference)
//
#include <hip/hip_runtime.h>
#include <math.h>

#define IMG_H 512
#define IMG_W 512
#define NPLANES 48            // 16 * 3
#define RAD 5
#define TAPS 11
#define CHUNK 32              // 512/32 exact -> no y-bounds check, no wasted rows
#define STRIP 64              // columns per wave (one autonomous wave per strip)
#define WPB 2                 // waves per block (128 threads) -> 3072 blocks
#define SBUF 80               // 74 used (64 + 2*RAD), padded
#define ROWB (IMG_W * 4)      // row stride, bytes
#define PLANEB (IMG_H * IMG_W * 4)

typedef float v2f __attribute__((ext_vector_type(2)));
typedef int   v4i __attribute__((ext_vector_type(4)));

// Raw buffer load with HARDWARE bounds check: SRD num_records = plane bytes,
// so any voffset outside [0, PLANEB) returns 0.0f with no memory traffic.
// Replaces ALL per-row software bounds logic (rows <0 / >=512 go OOB as the
// voffset marches; col<0 / tail col>=512 lanes poisoned once at setup).
__device__ float
llvm_amdgcn_raw_buffer_load_f32(v4i srsrc, int voffset, int soffset, int aux)
    __asm("llvm.amdgcn.raw.buffer.load.f32");

#define WAVE_FENCE_WAR()  __asm__ __volatile__("" ::: "memory")
#define WAVE_FENCE_RAW()  __asm__ __volatile__("s_waitcnt lgkmcnt(0)" ::: "memory")

struct GaussW { float w[TAPS]; };

// Structure notes (evidence-driven):
//  - R2/R7: ANY launch-bounds reg-cap below the kernel's ~104 unified
//    (VGPR+AGPR) footprint spills the 55-float ring to scratch:
//    WRITE_SIZE 48KB -> 213MB, 70us -> 219us. Keep the 128-reg budget.
//  - R7: union-built SRD defeated uniformity -> VGPR srsrc (waterfall risk).
//    Now each SRD word is forced through readfirstlane -> SGPR-resident.
//  - R5: one wave per 64-col strip, no block barriers. R6: packed fp32.
//  - R8 (this): revert reg cap; scalar SRD; CHUNK=32 (exact tiling, no
//    y-check); 2-wave blocks for granularity. WRITE_SIZE is the tripwire.
__global__ __launch_bounds__(128, 4)
void ssim_main(const float* __restrict__ img1, const float* __restrict__ img2,
               double* __restrict__ sum_ws, float* __restrict__ out, GaussW gw) {
    __shared__ float2 srow[WPB][SBUF]; // one private (a,b) row buffer per wave
    __shared__ float wsum[WPB];

    const int tid  = threadIdx.x;
    const int wid  = tid >> 6;         // wave id 0..1
    const int lane = tid & 63;
    const int c0   = blockIdx.x * (WPB * STRIP) + wid * STRIP;  // strip base col
    const int y0   = blockIdx.y * CHUNK;
    const size_t pbase = (size_t)blockIdx.z * (IMG_H * IMG_W);
    float2* buf = srow[wid];

    // Per-plane SRDs, force-scalarized word by word (readfirstlane -> SGPR).
    // word2 = num_records BYTES (stride==0); word3 = 0x00020000 raw dword.
    v4i srd1, srd2;
    {
        const float* p1 = img1 + pbase;
        const float* p2 = img2 + pbase;
        int a0 = __builtin_amdgcn_readfirstlane((int)(unsigned)(uintptr_t)p1);
        int a1 = __builtin_amdgcn_readfirstlane((int)((uintptr_t)p1 >> 32));
        int b0 = __builtin_amdgcn_readfirstlane((int)(unsigned)(uintptr_t)p2);
        int b1 = __builtin_amdgcn_readfirstlane((int)((uintptr_t)p2 >> 32));
        srd1 = (v4i){a0, a1, PLANEB, 0x00020000};
        srd2 = (v4i){b0, b1, PLANEB, 0x00020000};
    }

    // Row-invariant voffsets; per row just += ROWB. Negative prologue offsets
    // are huge-unsigned (OOB -> 0) and advance into range when the row is
    // valid. Poison (1 GiB) stays OOB for all 43 increments.
    const int colm = c0 - RAD + lane;              // buf idx = lane
    int vo = (y0 - RAD) * ROWB + colm * 4;
    if (colm < 0) vo = 0x40000000;                 // col<0 would alias prev row
    const int c2 = c0 + STRIP - RAD + lane;        // buf idx = 64+lane (lane<10)
    int vt = (y0 - RAD) * ROWB + c2 * 4;
    if (lane >= 2 * RAD || c2 >= IMG_W) vt = 0x40000000;

    // register ring, 11 rows deep:
    //   rab = (conv_h(a), conv_h(b)), rsq = (conv_h(a^2), conv_h(b^2)), rx = conv_h(ab)
    v2f rab[TAPS], rsq[TAPS];
    float rx[TAPS];

    float pa, pb, pta, ptb;            // prefetch registers for the next row

    auto load_regs = [&]() {
        pa  = llvm_amdgcn_raw_buffer_load_f32(srd1, vo, 0, 0);
        pb  = llvm_amdgcn_raw_buffer_load_f32(srd2, vo, 0, 0);
        pta = llvm_amdgcn_raw_buffer_load_f32(srd1, vt, 0, 0);
        ptb = llvm_amdgcn_raw_buffer_load_f32(srd2, vt, 0, 0);
        vo += ROWB; vt += ROWB;
    };

    auto store_lds = [&]() {
        WAVE_FENCE_WAR();              // don't sink writes above prior reads
        buf[lane] = make_float2(pa, pb);
        if (lane < 2 * RAD) buf[STRIP + lane] = make_float2(pta, ptb);
        WAVE_FENCE_RAW();              // don't hoist following reads above it
    };

    // packed horizontal conv: per tap 1 pk_mul + 1 mul + 2 pk_fma + 1 fma.
    // No row guard: OOB rows stored zeros -> contribute w*0 (exact).
    auto hconv = [&](v2f& oab, v2f& osq, float& ox) {
        v2f aab = {0.f, 0.f}, asq = {0.f, 0.f};
        float ax = 0.f;
        #pragma unroll
        for (int d = 0; d < TAPS; ++d) {
            v2f v = *(const v2f*)&buf[lane + d];   // (a, b)
            float w = gw.w[d];
            v2f wv = {w, w};
            aab = __builtin_elementwise_fma(wv, v, aab);          // pk_fma
            v2f sq = v * v;                                       // pk_mul
            asq = __builtin_elementwise_fma(wv, sq, asq);         // pk_fma
            ax  = fmaf(w, v.x * v.y, ax);                         // mul+fma
        }
        oab = aab; osq = asq; ox = ax;
    };

    const float C1v = 0.0001f;  // 0.01^2
    const float C2v = 0.0009f;  // 0.03^2
    float acc = 0.f;

    // One output row: publish prefetched input row, start next row's loads,
    // hconv into ring slot (J+10)%11, then vconv (ring phase J, all static).
    #define PROC_ROW(J)                                                        \
    {                                                                          \
        store_lds();                                                           \
        load_regs();                                                           \
        hconv(rab[((J) + 10) % TAPS], rsq[((J) + 10) % TAPS],                  \
              rx[((J) + 10) % TAPS]);                                          \
        v2f mu = {0.f, 0.f}, s2 = {0.f, 0.f};                                  \
        float sx = 0.f;                                                        \
        _Pragma("unroll")                                                      \
        for (int t = 0; t < TAPS; ++t) {                                       \
            const int s = ((J) + t) % TAPS;  /* static */                      \
            float w = gw.w[t];                                                 \
            v2f wv = {w, w};                                                   \
            mu = __builtin_elementwise_fma(wv, rab[s], mu);                    \
            s2 = __builtin_elementwise_fma(wv, rsq[s], s2);                    \
            sx = fmaf(w, rx[s], sx);                                           \
        }                                                                      \
        float mu1 = mu.x, mu2 = mu.y;                                          \
        float mu1sq = mu1 * mu1, mu2sq = mu2 * mu2, mu12 = mu1 * mu2;          \
        float sg1 = s2.x - mu1sq, sg2 = s2.y - mu2sq, sg12 = sx - mu12;        \
        float num = (2.f * mu12 + C1v) * (2.f * sg12 + C2v);                   \
        float den = (mu1sq + mu2sq + C1v) * (sg1 + sg2 + C2v);                 \
        acc += num * __builtin_amdgcn_rcpf(den);                               \
    }

    // ---- prologue: h-rows for global rows y0-5 .. y0+4 -> ring slots 0..9
    load_regs();
    #pragma unroll
    for (int k = 0; k < TAPS - 1; ++k) {
        store_lds();
        load_regs();                   // next row's loads in flight during hconv
        hconv(rab[k], rsq[k], rx[k]);
    }

    // ---- main: 32 output rows = 2 x 11 (looped, shared code) + 10 tail.
    // Ring phase after 22 rows is 22%11 == 0, so the tail reuses the same
    // static indices; y = y0 + row is always < 512 (CHUNK divides 512).
    for (int kk = 0; kk < 22; kk += TAPS) {
        PROC_ROW(0)  PROC_ROW(1)  PROC_ROW(2)  PROC_ROW(3)  PROC_ROW(4)
        PROC_ROW(5)  PROC_ROW(6)  PROC_ROW(7)  PROC_ROW(8)  PROC_ROW(9)
        PROC_ROW(10)
    }
    PROC_ROW(0)  PROC_ROW(1)  PROC_ROW(2)  PROC_ROW(3)  PROC_ROW(4)
    PROC_ROW(5)  PROC_ROW(6)  PROC_ROW(7)  PROC_ROW(8)  PROC_ROW(9)

    #undef PROC_ROW

    // wave (64-lane) shuffle reduce -> block partials -> one atomic per block
    #pragma unroll
    for (int off = 32; off > 0; off >>= 1) acc += __shfl_down(acc, off, 64);
    if (lane == 0) wsum[wid] = acc;
    __syncthreads();                   // only block barrier in the kernel
    if (tid == 0) {
        double s = (double)wsum[0] + (double)wsum[1];
        atomicAdd(sum_ws, s);
        // last block finalizes: device-scope atomics + fences (XCD-safe)
        __threadfence();
        unsigned* ctr = (unsigned*)(sum_ws + 1);
        unsigned nb = gridDim.x * gridDim.y * gridDim.z;
        if (atomicAdd(ctr, 1u) == nb - 1u) {
            __threadfence();
            double total = atomicAdd(sum_ws, 0.0);   // coherent read of final sum
            out[0] = (float)(total * (1.0 / (16.0 * 3.0 * 512.0 * 512.0)));
        }
    }
}

extern "C" void kernel_launch(void* const* d_in, const int* in_sizes, int n_in,
                              void* d_out, int out_size, void* d_ws, size_t ws_size,
                              hipStream_t stream) {
    const float* img1 = (const float*)d_in[0];
    const float* img2 = (const float*)d_in[1];
    float* out = (float*)d_out;
    double* ws = (double*)d_ws;

    // d_ws poisoned 0xAA before every launch — zero accumulator + done-counter
    hipMemsetAsync(ws, 0, 2 * sizeof(double), stream);

    // Gaussian weights computed on host in double, passed via kernarg (SGPRs)
    GaussW gw;
    double g[TAPS], s = 0.0;
    for (int i = 0; i < TAPS; ++i) {
        double x = (double)(i - TAPS / 2);
        g[i] = exp(-(x * x) / (2.0 * 1.5 * 1.5));
        s += g[i];
    }
    for (int i = 0; i < TAPS; ++i) gw.w[i] = (float)(g[i] / s);

    // 4 x 16 x 48 = 3072 blocks; each block = 2 autonomous 64-col wave strips
    dim3 grid(IMG_W / (WPB * STRIP), IMG_H / CHUNK, NPLANES);
    ssim_main<<<grid, WPB * 64, 0, stream>>>(img1, img2, ws, out, gw);
}

// Round 3
// 307.045 us; speedup vs baseline: 1.9895x; 1.9895x over previous
//
#include <hip/hip_runtime.h>
#include <math.h>

#define IMG_H 512
#define IMG_W 512
#define NPLANES 48            // 16 * 3
#define RAD 5
#define TAPS 11
#define CHUNK 16              // 512/16 exact; 2x32x48 = 3072 blocks = 3 FULL
                              // residency waves (1024 co-resident at 4 blk/CU)
#define STRIP 64              // columns per wave (one autonomous wave per strip)
#define SBUF 80               // 74 used (64 + 2*RAD), padded

typedef float v2f __attribute__((ext_vector_type(2)));

// Compiler-only fence: cross-lane LDS dependence (lane i reads what lane j
// wrote) is INVISIBLE to LLVM alias analysis — R4 failed correctness exactly
// this way (reads hoisted above writes once __syncthreads was removed).
// HW needs nothing: wave has one PC and same-wave DS ops complete in order.
#define WAVE_FENCE_WAR()  __asm__ __volatile__("" ::: "memory")
#define WAVE_FENCE_RAW()  __asm__ __volatile__("s_waitcnt lgkmcnt(0)" ::: "memory")

struct GaussW { float w[TAPS]; };

// Structure notes (evidence-driven):
//  - R2/R7(256,5)+SRD/R8(128,4)+SRD: raw-buffer-load rewrite + any reg-cap
//    below the ~104 unified (VGPR+AGPR) footprint spills the 55-float ring:
//    WRITE_SIZE 48KB -> 213MB/846MB, 70us -> 219/530us. The ring lives in
//    AGPRs only with THIS load path (plain pointer loads, VGPR_Count=40).
//    DO NOT touch the load path; WRITE_SIZE is the spill tripwire.
//  - R3: block-wide barriers were lockstep; R5: one wave per 64-col strip,
//    no block barriers. R6: packed fp32 (v_pk_fma).
//  - R9 (this): CHUNK 33->16. 1536 blocks was 1.5 residency waves (2nd wave
//    half-empty, ~75% util); 3072 blocks = 3 full waves. Exact 512/16 also
//    kills the y-bounds check + 16 wasted tail rows. Finalize folded into
//    last block (device-scope atomics, proven in R7/R8).
__global__ __launch_bounds__(256, 4)
void ssim_main(const float* __restrict__ img1, const float* __restrict__ img2,
               double* __restrict__ sum_ws, float* __restrict__ out, GaussW gw) {
    __shared__ float2 srow[4][SBUF];   // one private (a,b) row buffer per wave
    __shared__ float wsum[4];

    const int tid  = threadIdx.x;
    const int wid  = tid >> 6;         // wave id 0..3
    const int lane = tid & 63;
    const int c0   = blockIdx.x * (4 * STRIP) + wid * STRIP;  // strip base col
    const int y0   = blockIdx.y * CHUNK;
    const size_t pbase = (size_t)blockIdx.z * (IMG_H * IMG_W);
    const float* p1 = img1 + pbase;
    const float* p2 = img2 + pbase;
    float2* buf = srow[wid];

    // register ring, 11 rows deep:
    //   rab = (conv_h(a), conv_h(b))   packed
    //   rsq = (conv_h(a^2), conv_h(b^2)) packed
    //   rx  = conv_h(a*b)              scalar
    v2f rab[TAPS], rsq[TAPS];
    float rx[TAPS];

    // prefetch registers for the next row (main col + 10-col tail)
    float pa, pb, pta, ptb;

    auto load_regs = [&](int r) {
        pa = pb = pta = ptb = 0.f;
        if (r >= 0 && r < IMG_H) {     // wave-uniform
            const float* row1 = p1 + (size_t)r * IMG_W;
            const float* row2 = p2 + (size_t)r * IMG_W;
            int col = c0 - RAD + lane;              // buf idx = lane
            if (col >= 0 && col < IMG_W) { pa = row1[col]; pb = row2[col]; }
            if (lane < 2 * RAD) {                   // buf idx = 64+lane
                int c2 = c0 + STRIP - RAD + lane;   // cols c0+59..c0+68
                if (c2 < IMG_W) { pta = row1[c2]; ptb = row2[c2]; }
            }
        }
    };

    auto store_lds = [&]() {
        WAVE_FENCE_WAR();              // don't sink this write above prior reads
        buf[lane] = make_float2(pa, pb);
        if (lane < 2 * RAD) buf[STRIP + lane] = make_float2(pta, ptb);
        WAVE_FENCE_RAW();              // don't hoist following reads above it
    };

    // packed horizontal conv: per tap 1 pk_mul + 1 mul + 2 pk_fma + 1 fma
    auto hconv = [&](int r, v2f& oab, v2f& osq, float& ox) {
        v2f aab = {0.f, 0.f}, asq = {0.f, 0.f};
        float ax = 0.f;
        if (r >= 0 && r < IMG_H) {     // wave-uniform: padded rows contribute zero
            #pragma unroll
            for (int d = 0; d < TAPS; ++d) {
                v2f v = *(const v2f*)&buf[lane + d];   // (a, b)
                float w = gw.w[d];
                v2f wv = {w, w};
                aab = __builtin_elementwise_fma(wv, v, aab);          // pk_fma
                v2f sq = v * v;                                       // pk_mul
                asq = __builtin_elementwise_fma(wv, sq, asq);         // pk_fma
                ax  = fmaf(w, v.x * v.y, ax);                         // mul+fma
            }
        }
        oab = aab; osq = asq; ox = ax;
    };

    // ---- prologue: h-rows 0..9 (global rows y0-5 .. y0+4) -> ring slots 0..9
    load_regs(y0 - RAD);
    #pragma unroll
    for (int k = 0; k < TAPS - 1; ++k) {
        const int r = y0 - RAD + k;
        store_lds();
        load_regs(r + 1);              // next row's loads in flight during hconv
        hconv(r, rab[k], rsq[k], rx[k]);
    }

    const float C1v = 0.0001f;  // 0.01^2
    const float C2v = 0.0009f;  // 0.03^2
    float acc = 0.f;

    // One output row J (0..15): publish prefetched input row y0+5+J, issue
    // loads for the next, hconv into ring slot (J+10)%11, vconv at phase J%11.
    // All ring indices constant-folded (J is a literal). y = y0+J < 512 always
    // (CHUNK divides 512) -> no y-bounds check.
    #define PROC_ROW(J)                                                        \
    {                                                                          \
        const int r = y0 + RAD + (J);  /* input row entering the ring */       \
        store_lds();                                                           \
        load_regs(r + 1);                                                      \
        hconv(r, rab[((J) + 10) % TAPS], rsq[((J) + 10) % TAPS],               \
              rx[((J) + 10) % TAPS]);                                          \
        v2f mu = {0.f, 0.f}, s2 = {0.f, 0.f};                                  \
        float sx = 0.f;                                                        \
        _Pragma("unroll")                                                      \
        for (int t = 0; t < TAPS; ++t) {                                       \
            const int s = ((J) + t) % TAPS;  /* static */                      \
            float w = gw.w[t];                                                 \
            v2f wv = {w, w};                                                   \
            mu = __builtin_elementwise_fma(wv, rab[s], mu);                    \
            s2 = __builtin_elementwise_fma(wv, rsq[s], s2);                    \
            sx = fmaf(w, rx[s], sx);                                           \
        }                                                                      \
        float mu1 = mu.x, mu2 = mu.y;                                          \
        float mu1sq = mu1 * mu1, mu2sq = mu2 * mu2, mu12 = mu1 * mu2;          \
        float sg1 = s2.x - mu1sq, sg2 = s2.y - mu2sq, sg12 = sx - mu12;        \
        float num = (2.f * mu12 + C1v) * (2.f * sg12 + C2v);                   \
        float den = (mu1sq + mu2sq + C1v) * (sg1 + sg2 + C2v);                 \
        acc += num * __builtin_amdgcn_rcpf(den);                               \
    }

    PROC_ROW(0)  PROC_ROW(1)  PROC_ROW(2)  PROC_ROW(3)
    PROC_ROW(4)  PROC_ROW(5)  PROC_ROW(6)  PROC_ROW(7)
    PROC_ROW(8)  PROC_ROW(9)  PROC_ROW(10) PROC_ROW(11)
    PROC_ROW(12) PROC_ROW(13) PROC_ROW(14) PROC_ROW(15)

    #undef PROC_ROW

    // wave (64-lane) shuffle reduce -> block partials -> one atomic per block
    #pragma unroll
    for (int off = 32; off > 0; off >>= 1) acc += __shfl_down(acc, off, 64);
    if (lane == 0) wsum[wid] = acc;
    __syncthreads();                   // only block barrier in the kernel
    if (tid == 0) {
        double s = (double)wsum[0] + (double)wsum[1] + (double)wsum[2] + (double)wsum[3];
        atomicAdd(sum_ws, s);
        // last block finalizes: device-scope atomics + fences (XCD-safe).
        // Proven correct in R7/R8 (absmax 0.0 both rounds).
        __threadfence();
        unsigned* ctr = (unsigned*)(sum_ws + 1);
        unsigned nb = gridDim.x * gridDim.y * gridDim.z;
        if (atomicAdd(ctr, 1u) == nb - 1u) {
            __threadfence();
            double total = atomicAdd(sum_ws, 0.0);   // coherent read of final sum
            out[0] = (float)(total * (1.0 / (16.0 * 3.0 * 512.0 * 512.0)));
        }
    }
}

extern "C" void kernel_launch(void* const* d_in, const int* in_sizes, int n_in,
                              void* d_out, int out_size, void* d_ws, size_t ws_size,
                              hipStream_t stream) {
    const float* img1 = (const float*)d_in[0];
    const float* img2 = (const float*)d_in[1];
    float* out = (float*)d_out;
    double* ws = (double*)d_ws;

    // d_ws is poisoned 0xAA before every launch — zero accumulator + counter
    hipMemsetAsync(ws, 0, 2 * sizeof(double), stream);

    // Gaussian weights computed on host in double, passed via kernarg (SGPRs)
    GaussW gw;
    double g[TAPS], s = 0.0;
    for (int i = 0; i < TAPS; ++i) {
        double x = (double)(i - TAPS / 2);
        g[i] = exp(-(x * x) / (2.0 * 1.5 * 1.5));
        s += g[i];
    }
    for (int i = 0; i < TAPS; ++i) gw.w[i] = (float)(g[i] / s);

    // 2 x 32 x 48 = 3072 blocks = 3 exact residency waves at 4 blocks/CU;
    // each block = 4 autonomous 64-col wave strips
    dim3 grid(IMG_W / (4 * STRIP), IMG_H / CHUNK, NPLANES);
    ssim_main<<<grid, 256, 0, stream>>>(img1, img2, ws, out, gw);
}

// Round 5
// 198.861 us; speedup vs baseline: 3.0718x; 1.5440x over previous
//
#include <hip/hip_runtime.h>
#include <math.h>

#define IMG_H 512
#define IMG_W 512
#define NPLANES 48            // 16 * 3
#define RAD 5
#define TAPS 11
#define CHUNK 33              // multiple of 11 -> static ring phase after unroll
#define STRIP 64              // columns per wave (one autonomous wave per strip)
#define SBUF 80               // 74 used (64 + 2*RAD), padded

typedef float v2f __attribute__((ext_vector_type(2)));

// Compiler-only fence: cross-lane LDS dependence (lane i reads what lane j
// wrote) is INVISIBLE to LLVM alias analysis — R4 failed correctness exactly
// this way (reads hoisted above writes once __syncthreads was removed).
// HW needs nothing: wave has one PC and same-wave DS ops complete in order.
#define WAVE_FENCE_WAR()  __asm__ __volatile__("" ::: "memory")
#define WAVE_FENCE_RAW()  __asm__ __volatile__("s_waitcnt lgkmcnt(0)" ::: "memory")

struct GaussW { float w[TAPS]; };

// Structure notes (evidence-driven). The 55-float ring lives in the unified
// AGPR half ONLY under this exact structure; three independent spill triggers
// are now proven (WRITE_SIZE 48KB -> 92..846MB, kernel 70 -> 219..530us):
//  - R2/R7: any launch-bounds reg cap below the ~104 unified footprint
//    ((256,5)/(256,6)) spills the ring. Keep (256,4) = 128-reg budget.
//  - R8/R9: FULL straight-line unroll of the row loop (macro PROC_ROW) lets
//    the scheduler pipeline loads across all rows -> pressure explosion.
//    Keep the `for kk` loop + 11-row `#pragma unroll` body EXACTLY.
//  - R7/R8: raw-buffer-SRD load path (never exonerated; moot). Keep plain
//    pointer loads with software bounds.
//  - R3: block-wide __syncthreads per staged row was lockstep (VALUBusy 42%).
//    R5: one wave per 64-col strip, no block barriers -> 77us, VALUBusy 70%.
//    R6: packed fp32 (v_pk_fma).
//  - R10/R11: R6 structure restored byte-for-byte; ONLY delta = finalize
//    folded into the last block (device-scope atomics, absmax 0.0 in
//    R7/R8/R9), removing one dispatch from the graph (~83us fixed overhead).
//    R10's bench run died to container failure (no verdict); R11 is the
//    identical source resubmitted. WRITE_SIZE is the spill tripwire.
__global__ __launch_bounds__(256, 4)
void ssim_main(const float* __restrict__ img1, const float* __restrict__ img2,
               double* __restrict__ sum_ws, float* __restrict__ out, int nb,
               GaussW gw) {
    __shared__ float2 srow[4][SBUF];   // one private (a,b) row buffer per wave
    __shared__ float wsum[4];

    const int tid  = threadIdx.x;
    const int wid  = tid >> 6;         // wave id 0..3
    const int lane = tid & 63;
    const int c0   = blockIdx.x * (4 * STRIP) + wid * STRIP;  // strip base col
    const int y0   = blockIdx.y * CHUNK;
    const size_t pbase = (size_t)blockIdx.z * (IMG_H * IMG_W);
    const float* p1 = img1 + pbase;
    const float* p2 = img2 + pbase;
    float2* buf = srow[wid];

    // register ring, 11 rows deep:
    //   rab = (conv_h(a), conv_h(b))   packed
    //   rsq = (conv_h(a^2), conv_h(b^2)) packed
    //   rx  = conv_h(a*b)              scalar
    v2f rab[TAPS], rsq[TAPS];
    float rx[TAPS];

    // prefetch registers for the next row (main col + 10-col tail)
    float pa, pb, pta, ptb;

    auto load_regs = [&](int r) {
        pa = pb = pta = ptb = 0.f;
        if (r >= 0 && r < IMG_H) {     // wave-uniform
            const float* row1 = p1 + (size_t)r * IMG_W;
            const float* row2 = p2 + (size_t)r * IMG_W;
            int col = c0 - RAD + lane;              // buf idx = lane
            if (col >= 0 && col < IMG_W) { pa = row1[col]; pb = row2[col]; }
            if (lane < 2 * RAD) {                   // buf idx = 64+lane
                int c2 = c0 + STRIP - RAD + lane;   // cols c0+59..c0+68
                if (c2 < IMG_W) { pta = row1[c2]; ptb = row2[c2]; }
            }
        }
    };

    auto store_lds = [&]() {
        WAVE_FENCE_WAR();              // don't sink this write above prior reads
        buf[lane] = make_float2(pa, pb);
        if (lane < 2 * RAD) buf[STRIP + lane] = make_float2(pta, ptb);
        WAVE_FENCE_RAW();              // don't hoist following reads above it
    };

    // packed horizontal conv: per tap 1 pk_mul + 1 mul + 2 pk_fma + 1 fma
    auto hconv = [&](int r, v2f& oab, v2f& osq, float& ox) {
        v2f aab = {0.f, 0.f}, asq = {0.f, 0.f};
        float ax = 0.f;
        if (r >= 0 && r < IMG_H) {     // wave-uniform: padded rows contribute zero
            #pragma unroll
            for (int d = 0; d < TAPS; ++d) {
                v2f v = *(const v2f*)&buf[lane + d];   // (a, b)
                float w = gw.w[d];
                v2f wv = {w, w};
                aab = __builtin_elementwise_fma(wv, v, aab);          // pk_fma
                v2f sq = v * v;                                       // pk_mul
                asq = __builtin_elementwise_fma(wv, sq, asq);         // pk_fma
                ax  = fmaf(w, v.x * v.y, ax);                         // mul+fma
            }
        }
        oab = aab; osq = asq; ox = ax;
    };

    // ---- prologue: h-rows 0..9 (global rows y0-5 .. y0+4) -> ring slots 0..9
    load_regs(y0 - RAD);
    #pragma unroll
    for (int k = 0; k < TAPS - 1; ++k) {
        const int r = y0 - RAD + k;
        store_lds();
        load_regs(r + 1);              // next row's loads in flight during hconv
        hconv(r, rab[k], rsq[k], rx[k]);
    }

    const float C1v = 0.0001f;  // 0.01^2
    const float C2v = 0.0009f;  // 0.03^2
    float acc = 0.f;

    // ---- main: CHUNK output rows, unrolled by 11 so ring indices are static
    for (int kk = 0; kk < CHUNK; kk += TAPS) {
        #pragma unroll
        for (int j = 0; j < TAPS; ++j) {
            const int r = y0 - RAD + (TAPS - 1) + kk + j;  // global input row
            store_lds();               // publish prefetched row r
            load_regs(r + 1);          // issue loads for row r+1 NOW
            hconv(r, rab[(j + 10) % TAPS], rsq[(j + 10) % TAPS], rx[(j + 10) % TAPS]);

            const int y = y0 + kk + j; // output row
            if (y < IMG_H) {
                // packed vertical conv: per tap 2 pk_fma + 1 fma
                v2f mu = {0.f, 0.f}, s2 = {0.f, 0.f};
                float sx = 0.f;
                #pragma unroll
                for (int t = 0; t < TAPS; ++t) {
                    const int s = (j + t) % TAPS;  // static after unroll
                    float w = gw.w[t];
                    v2f wv = {w, w};
                    mu = __builtin_elementwise_fma(wv, rab[s], mu);
                    s2 = __builtin_elementwise_fma(wv, rsq[s], s2);
                    sx = fmaf(w, rx[s], sx);
                }
                float mu1 = mu.x, mu2 = mu.y;
                float mu1sq = mu1 * mu1, mu2sq = mu2 * mu2, mu12 = mu1 * mu2;
                float sg1 = s2.x - mu1sq, sg2 = s2.y - mu2sq, sg12 = sx - mu12;
                float num = (2.f * mu12 + C1v) * (2.f * sg12 + C2v);
                float den = (mu1sq + mu2sq + C1v) * (sg1 + sg2 + C2v);
                acc += num * __builtin_amdgcn_rcpf(den);
            }
        }
    }

    // wave (64-lane) shuffle reduce -> block partials -> one atomic per block
    #pragma unroll
    for (int off = 32; off > 0; off >>= 1) acc += __shfl_down(acc, off, 64);
    if (lane == 0) wsum[wid] = acc;
    __syncthreads();                   // only block barrier in the kernel
    if (tid == 0) {
        double s = (double)wsum[0] + (double)wsum[1] + (double)wsum[2] + (double)wsum[3];
        atomicAdd(sum_ws, s);
        // last block finalizes: device-scope atomics + fences (XCD-safe).
        // Proven correct in R7/R8/R9 (absmax 0.0 each round).
        __threadfence();
        unsigned* ctr = (unsigned*)(sum_ws + 1);
        if (atomicAdd(ctr, 1u) == (unsigned)nb - 1u) {
            __threadfence();
            double total = atomicAdd(sum_ws, 0.0);   // coherent read of final sum
            out[0] = (float)(total * (1.0 / (16.0 * 3.0 * 512.0 * 512.0)));
        }
    }
}

extern "C" void kernel_launch(void* const* d_in, const int* in_sizes, int n_in,
                              void* d_out, int out_size, void* d_ws, size_t ws_size,
                              hipStream_t stream) {
    const float* img1 = (const float*)d_in[0];
    const float* img2 = (const float*)d_in[1];
    float* out = (float*)d_out;
    double* ws = (double*)d_ws;

    // d_ws is poisoned 0xAA before every launch — zero accumulator + counter
    hipMemsetAsync(ws, 0, 2 * sizeof(double), stream);

    // Gaussian weights computed on host in double, passed via kernarg (SGPRs)
    GaussW gw;
    double g[TAPS], s = 0.0;
    for (int i = 0; i < TAPS; ++i) {
        double x = (double)(i - TAPS / 2);
        g[i] = exp(-(x * x) / (2.0 * 1.5 * 1.5));
        s += g[i];
    }
    for (int i = 0; i < TAPS; ++i) gw.w[i] = (float)(g[i] / s);

    // 2 x 16 x 48 = 1536 blocks (= exactly 6 per CU); each block = 4
    // autonomous 64-col wave strips
    dim3 grid(IMG_W / (4 * STRIP), (IMG_H + CHUNK - 1) / CHUNK, NPLANES);
    const int nb = grid.x * grid.y * grid.z;
    ssim_main<<<grid, 256, 0, stream>>>(img1, img2, ws, out, nb, gw);
}

// Round 6
// 192.088 us; speedup vs baseline: 3.1801x; 1.0353x over previous
//
#include <hip/hip_runtime.h>
#include <math.h>

#define IMG_H 512
#define IMG_W 512
#define NPLANES 48            // 16 * 3
#define RAD 5
#define TAPS 11
#define CHUNK 33              // multiple of 11 -> static ring phase after unroll
#define STRIP 64              // columns per wave (one autonomous wave per strip)
#define SBUF 80               // 74 used (64 + 2*RAD), padded

typedef float v2f __attribute__((ext_vector_type(2)));

// Compiler-only fence: cross-lane LDS dependence (lane i reads what lane j
// wrote) is INVISIBLE to LLVM alias analysis — R4 failed correctness exactly
// this way (reads hoisted above writes once __syncthreads was removed).
// HW needs nothing: wave has one PC and same-wave DS ops complete in order.
#define WAVE_FENCE_WAR()  __asm__ __volatile__("" ::: "memory")
#define WAVE_FENCE_RAW()  __asm__ __volatile__("s_waitcnt lgkmcnt(0)" ::: "memory")

struct GaussW { float w[TAPS]; };

// Structure notes (evidence-driven). The 55-float ring lives in the unified
// AGPR half ONLY under this exact structure; proven failure triggers:
//  - R2/R7: any launch-bounds reg cap below the ~104 unified footprint
//    ((256,5)/(256,6)) spills the ring (WRITE_SIZE 48KB -> 200+MB). Keep
//    (256,4) = 128-reg budget.
//  - R8/R9: FULL straight-line unroll of the row loop lets the scheduler
//    pipeline loads across all rows -> pressure explosion -> spill. Keep
//    the `for kk` loop + 11-row `#pragma unroll` body EXACTLY.
//  - R7/R8: raw-buffer-SRD load path (never exonerated; moot). Keep plain
//    pointer loads with software bounds.
//  - R11: per-block __threadfence() = agent fence = per-XCD L2 maintenance
//    x1536 -> continuous L2 invalidation storm. Kernel 70 -> 116us with
//    IDENTICAL busy cycles (VALUBusy 67 -> 40 = 0.67/1.66) and IDENTICAL
//    FETCH (L3 absorbed the demoted reuse). All cross-WG data here moves
//    through device-scope atomics (coherence point), so the required
//    ordering is only: release on the ctr increment (cheap: waitcnt +
//    writeback of an essentially-clean L2) + acquire in the ONE winner
//    block. Scoped atomics express exactly that.
//  - R3: block-wide __syncthreads per staged row was lockstep. R5: one wave
//    per 64-col strip, no block barriers. R6: packed fp32 (v_pk_fma).
__global__ __launch_bounds__(256, 4)
void ssim_main(const float* __restrict__ img1, const float* __restrict__ img2,
               double* __restrict__ sum_ws, float* __restrict__ out, int nb,
               GaussW gw) {
    __shared__ float2 srow[4][SBUF];   // one private (a,b) row buffer per wave
    __shared__ float wsum[4];

    const int tid  = threadIdx.x;
    const int wid  = tid >> 6;         // wave id 0..3
    const int lane = tid & 63;
    const int c0   = blockIdx.x * (4 * STRIP) + wid * STRIP;  // strip base col
    const int y0   = blockIdx.y * CHUNK;
    const size_t pbase = (size_t)blockIdx.z * (IMG_H * IMG_W);
    const float* p1 = img1 + pbase;
    const float* p2 = img2 + pbase;
    float2* buf = srow[wid];

    // register ring, 11 rows deep:
    //   rab = (conv_h(a), conv_h(b))   packed
    //   rsq = (conv_h(a^2), conv_h(b^2)) packed
    //   rx  = conv_h(a*b)              scalar
    v2f rab[TAPS], rsq[TAPS];
    float rx[TAPS];

    // prefetch registers for the next row (main col + 10-col tail)
    float pa, pb, pta, ptb;

    auto load_regs = [&](int r) {
        pa = pb = pta = ptb = 0.f;
        if (r >= 0 && r < IMG_H) {     // wave-uniform
            const float* row1 = p1 + (size_t)r * IMG_W;
            const float* row2 = p2 + (size_t)r * IMG_W;
            int col = c0 - RAD + lane;              // buf idx = lane
            if (col >= 0 && col < IMG_W) { pa = row1[col]; pb = row2[col]; }
            if (lane < 2 * RAD) {                   // buf idx = 64+lane
                int c2 = c0 + STRIP - RAD + lane;   // cols c0+59..c0+68
                if (c2 < IMG_W) { pta = row1[c2]; ptb = row2[c2]; }
            }
        }
    };

    auto store_lds = [&]() {
        WAVE_FENCE_WAR();              // don't sink this write above prior reads
        buf[lane] = make_float2(pa, pb);
        if (lane < 2 * RAD) buf[STRIP + lane] = make_float2(pta, ptb);
        WAVE_FENCE_RAW();              // don't hoist following reads above it
    };

    // packed horizontal conv: per tap 1 pk_mul + 1 mul + 2 pk_fma + 1 fma
    auto hconv = [&](int r, v2f& oab, v2f& osq, float& ox) {
        v2f aab = {0.f, 0.f}, asq = {0.f, 0.f};
        float ax = 0.f;
        if (r >= 0 && r < IMG_H) {     // wave-uniform: padded rows contribute zero
            #pragma unroll
            for (int d = 0; d < TAPS; ++d) {
                v2f v = *(const v2f*)&buf[lane + d];   // (a, b)
                float w = gw.w[d];
                v2f wv = {w, w};
                aab = __builtin_elementwise_fma(wv, v, aab);          // pk_fma
                v2f sq = v * v;                                       // pk_mul
                asq = __builtin_elementwise_fma(wv, sq, asq);         // pk_fma
                ax  = fmaf(w, v.x * v.y, ax);                         // mul+fma
            }
        }
        oab = aab; osq = asq; ox = ax;
    };

    // ---- prologue: h-rows 0..9 (global rows y0-5 .. y0+4) -> ring slots 0..9
    load_regs(y0 - RAD);
    #pragma unroll
    for (int k = 0; k < TAPS - 1; ++k) {
        const int r = y0 - RAD + k;
        store_lds();
        load_regs(r + 1);              // next row's loads in flight during hconv
        hconv(r, rab[k], rsq[k], rx[k]);
    }

    const float C1v = 0.0001f;  // 0.01^2
    const float C2v = 0.0009f;  // 0.03^2
    float acc = 0.f;

    // ---- main: CHUNK output rows, unrolled by 11 so ring indices are static
    for (int kk = 0; kk < CHUNK; kk += TAPS) {
        #pragma unroll
        for (int j = 0; j < TAPS; ++j) {
            const int r = y0 - RAD + (TAPS - 1) + kk + j;  // global input row
            store_lds();               // publish prefetched row r
            load_regs(r + 1);          // issue loads for row r+1 NOW
            hconv(r, rab[(j + 10) % TAPS], rsq[(j + 10) % TAPS], rx[(j + 10) % TAPS]);

            const int y = y0 + kk + j; // output row
            if (y < IMG_H) {
                // packed vertical conv: per tap 2 pk_fma + 1 fma
                v2f mu = {0.f, 0.f}, s2 = {0.f, 0.f};
                float sx = 0.f;
                #pragma unroll
                for (int t = 0; t < TAPS; ++t) {
                    const int s = (j + t) % TAPS;  // static after unroll
                    float w = gw.w[t];
                    v2f wv = {w, w};
                    mu = __builtin_elementwise_fma(wv, rab[s], mu);
                    s2 = __builtin_elementwise_fma(wv, rsq[s], s2);
                    sx = fmaf(w, rx[s], sx);
                }
                float mu1 = mu.x, mu2 = mu.y;
                float mu1sq = mu1 * mu1, mu2sq = mu2 * mu2, mu12 = mu1 * mu2;
                float sg1 = s2.x - mu1sq, sg2 = s2.y - mu2sq, sg12 = sx - mu12;
                float num = (2.f * mu12 + C1v) * (2.f * sg12 + C2v);
                float den = (mu1sq + mu2sq + C1v) * (sg1 + sg2 + C2v);
                acc += num * __builtin_amdgcn_rcpf(den);
            }
        }
    }

    // wave (64-lane) shuffle reduce -> block partials -> one atomic per block
    #pragma unroll
    for (int off = 32; off > 0; off >>= 1) acc += __shfl_down(acc, off, 64);
    if (lane == 0) wsum[wid] = acc;
    __syncthreads();                   // only block barrier in the kernel
    if (tid == 0) {
        double s = (double)wsum[0] + (double)wsum[1] + (double)wsum[2] + (double)wsum[3];
        atomicAdd(sum_ws, s);          // device-scope coherent (coherence point)
        // Release on the increment orders the sum-atomic before it WITHOUT
        // per-block L2 invalidation (R11 lesson). Winner-only acquire.
        unsigned* ctr = (unsigned*)(sum_ws + 1);
        unsigned prev = __hip_atomic_fetch_add(ctr, 1u, __ATOMIC_RELEASE,
                                               __HIP_MEMORY_SCOPE_AGENT);
        if (prev == (unsigned)nb - 1u) {
            __builtin_amdgcn_fence(__ATOMIC_ACQUIRE, "agent");  // one, total
            double total = atomicAdd(sum_ws, 0.0);  // atomic read, coherent
            out[0] = (float)(total * (1.0 / (16.0 * 3.0 * 512.0 * 512.0)));
        }
    }
}

extern "C" void kernel_launch(void* const* d_in, const int* in_sizes, int n_in,
                              void* d_out, int out_size, void* d_ws, size_t ws_size,
                              hipStream_t stream) {
    const float* img1 = (const float*)d_in[0];
    const float* img2 = (const float*)d_in[1];
    float* out = (float*)d_out;
    double* ws = (double*)d_ws;

    // d_ws is poisoned 0xAA before every launch — zero accumulator + counter
    hipMemsetAsync(ws, 0, 2 * sizeof(double), stream);

    // Gaussian weights computed on host in double, passed via kernarg (SGPRs)
    GaussW gw;
    double g[TAPS], s = 0.0;
    for (int i = 0; i < TAPS; ++i) {
        double x = (double)(i - TAPS / 2);
        g[i] = exp(-(x * x) / (2.0 * 1.5 * 1.5));
        s += g[i];
    }
    for (int i = 0; i < TAPS; ++i) gw.w[i] = (float)(g[i] / s);

    // 2 x 16 x 48 = 1536 blocks (= exactly 6 per CU); each block = 4
    // autonomous 64-col wave strips
    dim3 grid(IMG_W / (4 * STRIP), (IMG_H + CHUNK - 1) / CHUNK, NPLANES);
    const int nb = grid.x * grid.y * grid.z;
    ssim_main<<<grid, 256, 0, stream>>>(img1, img2, ws, out, nb, gw);
}

// Round 7
// 152.478 us; speedup vs baseline: 4.0062x; 1.2598x over previous
//
#include <hip/hip_runtime.h>
#include <math.h>

#define IMG_H 512
#define IMG_W 512
#define NPLANES 48            // 16 * 3
#define RAD 5
#define TAPS 11
#define CHUNK 33              // multiple of 11 -> static ring phase after unroll
#define STRIP 64              // columns per wave (one autonomous wave per strip)
#define SBUF 80               // 74 used (64 + 2*RAD), padded

typedef float v2f __attribute__((ext_vector_type(2)));

// Compiler-only fence: cross-lane LDS dependence (lane i reads what lane j
// wrote) is INVISIBLE to LLVM alias analysis — R4 failed correctness exactly
// this way (reads hoisted above writes once __syncthreads was removed).
// HW needs nothing: wave has one PC and same-wave DS ops complete in order.
#define WAVE_FENCE_WAR()  __asm__ __volatile__("" ::: "memory")
#define WAVE_FENCE_RAW()  __asm__ __volatile__("s_waitcnt lgkmcnt(0)" ::: "memory")

struct GaussW { float w[TAPS]; };

// Structure notes (evidence-driven). This is the R0/R6-session structure,
// restored byte-for-byte as a within-session ANCHOR. Ledger:
//  - R2/R7: any launch-bounds reg cap below the ~104 unified (VGPR+AGPR)
//    footprint spills the 55-float ring (WRITE_SIZE 48KB -> 200+MB,
//    70 -> 219+us). Keep (256,4) = 128-reg budget.
//  - R8/R9: FULL straight-line unroll of the row loop -> scheduler pipelines
//    loads across all rows -> pressure explosion -> spill. Keep the `for kk`
//    loop + 11-row `#pragma unroll` body EXACTLY.
//  - R7/R8: raw-buffer-SRD load path: never exonerated, abandoned.
//  - R10..R12: finalize-fold experiments. Fixed graph overhead is ~83us
//    REGARDLESS of dispatch count (R0: 3 dispatches, +83; R6: 2 dispatches,
//    +84) -> fold has no payoff. In-kernel cost of the folded tail vs this
//    anchor is confounded with container variance (busy-cycle product
//    conserved: 0.67x70 = 0.43x108); this round discriminates: A) kernel
//    ~70us here -> fold genuinely cost 38us, stays dead; B) kernel ~108us
//    -> container variance, judge future rounds within-container only.
//  - R3: block-wide __syncthreads per staged row was lockstep (VALUBusy 42%).
//    R5: one wave per 64-col strip, no block barriers -> VALUBusy 70%.
//    R6: packed fp32 (v_pk_fma).
__global__ __launch_bounds__(256, 4)
void ssim_main(const float* __restrict__ img1, const float* __restrict__ img2,
               double* __restrict__ sum_ws, GaussW gw) {
    __shared__ float2 srow[4][SBUF];   // one private (a,b) row buffer per wave
    __shared__ float wsum[4];

    const int tid  = threadIdx.x;
    const int wid  = tid >> 6;         // wave id 0..3
    const int lane = tid & 63;
    const int c0   = blockIdx.x * (4 * STRIP) + wid * STRIP;  // strip base col
    const int y0   = blockIdx.y * CHUNK;
    const size_t pbase = (size_t)blockIdx.z * (IMG_H * IMG_W);
    const float* p1 = img1 + pbase;
    const float* p2 = img2 + pbase;
    float2* buf = srow[wid];

    // register ring, 11 rows deep:
    //   rab = (conv_h(a), conv_h(b))   packed
    //   rsq = (conv_h(a^2), conv_h(b^2)) packed
    //   rx  = conv_h(a*b)              scalar
    v2f rab[TAPS], rsq[TAPS];
    float rx[TAPS];

    // prefetch registers for the next row (main col + 10-col tail)
    float pa, pb, pta, ptb;

    auto load_regs = [&](int r) {
        pa = pb = pta = ptb = 0.f;
        if (r >= 0 && r < IMG_H) {     // wave-uniform
            const float* row1 = p1 + (size_t)r * IMG_W;
            const float* row2 = p2 + (size_t)r * IMG_W;
            int col = c0 - RAD + lane;              // buf idx = lane
            if (col >= 0 && col < IMG_W) { pa = row1[col]; pb = row2[col]; }
            if (lane < 2 * RAD) {                   // buf idx = 64+lane
                int c2 = c0 + STRIP - RAD + lane;   // cols c0+59..c0+68
                if (c2 < IMG_W) { pta = row1[c2]; ptb = row2[c2]; }
            }
        }
    };

    auto store_lds = [&]() {
        WAVE_FENCE_WAR();              // don't sink this write above prior reads
        buf[lane] = make_float2(pa, pb);
        if (lane < 2 * RAD) buf[STRIP + lane] = make_float2(pta, ptb);
        WAVE_FENCE_RAW();              // don't hoist following reads above it
    };

    // packed horizontal conv: per tap 1 pk_mul + 1 mul + 2 pk_fma + 1 fma
    auto hconv = [&](int r, v2f& oab, v2f& osq, float& ox) {
        v2f aab = {0.f, 0.f}, asq = {0.f, 0.f};
        float ax = 0.f;
        if (r >= 0 && r < IMG_H) {     // wave-uniform: padded rows contribute zero
            #pragma unroll
            for (int d = 0; d < TAPS; ++d) {
                v2f v = *(const v2f*)&buf[lane + d];   // (a, b)
                float w = gw.w[d];
                v2f wv = {w, w};
                aab = __builtin_elementwise_fma(wv, v, aab);          // pk_fma
                v2f sq = v * v;                                       // pk_mul
                asq = __builtin_elementwise_fma(wv, sq, asq);         // pk_fma
                ax  = fmaf(w, v.x * v.y, ax);                         // mul+fma
            }
        }
        oab = aab; osq = asq; ox = ax;
    };

    // ---- prologue: h-rows 0..9 (global rows y0-5 .. y0+4) -> ring slots 0..9
    load_regs(y0 - RAD);
    #pragma unroll
    for (int k = 0; k < TAPS - 1; ++k) {
        const int r = y0 - RAD + k;
        store_lds();
        load_regs(r + 1);              // next row's loads in flight during hconv
        hconv(r, rab[k], rsq[k], rx[k]);
    }

    const float C1v = 0.0001f;  // 0.01^2
    const float C2v = 0.0009f;  // 0.03^2
    float acc = 0.f;

    // ---- main: CHUNK output rows, unrolled by 11 so ring indices are static
    for (int kk = 0; kk < CHUNK; kk += TAPS) {
        #pragma unroll
        for (int j = 0; j < TAPS; ++j) {
            const int r = y0 - RAD + (TAPS - 1) + kk + j;  // global input row
            store_lds();               // publish prefetched row r
            load_regs(r + 1);          // issue loads for row r+1 NOW
            hconv(r, rab[(j + 10) % TAPS], rsq[(j + 10) % TAPS], rx[(j + 10) % TAPS]);

            const int y = y0 + kk + j; // output row
            if (y < IMG_H) {
                // packed vertical conv: per tap 2 pk_fma + 1 fma
                v2f mu = {0.f, 0.f}, s2 = {0.f, 0.f};
                float sx = 0.f;
                #pragma unroll
                for (int t = 0; t < TAPS; ++t) {
                    const int s = (j + t) % TAPS;  // static after unroll
                    float w = gw.w[t];
                    v2f wv = {w, w};
                    mu = __builtin_elementwise_fma(wv, rab[s], mu);
                    s2 = __builtin_elementwise_fma(wv, rsq[s], s2);
                    sx = fmaf(w, rx[s], sx);
                }
                float mu1 = mu.x, mu2 = mu.y;
                float mu1sq = mu1 * mu1, mu2sq = mu2 * mu2, mu12 = mu1 * mu2;
                float sg1 = s2.x - mu1sq, sg2 = s2.y - mu2sq, sg12 = sx - mu12;
                float num = (2.f * mu12 + C1v) * (2.f * sg12 + C2v);
                float den = (mu1sq + mu2sq + C1v) * (sg1 + sg2 + C2v);
                acc += num * __builtin_amdgcn_rcpf(den);
            }
        }
    }

    // wave (64-lane) shuffle reduce -> block partials -> one atomic per block
    #pragma unroll
    for (int off = 32; off > 0; off >>= 1) acc += __shfl_down(acc, off, 64);
    if (lane == 0) wsum[wid] = acc;
    __syncthreads();                   // only block barrier in the kernel
    if (tid == 0) {
        double s = (double)wsum[0] + (double)wsum[1] + (double)wsum[2] + (double)wsum[3];
        atomicAdd(sum_ws, s);
    }
}

__global__ void ssim_finalize(const double* __restrict__ sum_ws, float* __restrict__ out) {
    out[0] = (float)(sum_ws[0] * (1.0 / (double)(16.0 * 3.0 * 512.0 * 512.0)));
}

extern "C" void kernel_launch(void* const* d_in, const int* in_sizes, int n_in,
                              void* d_out, int out_size, void* d_ws, size_t ws_size,
                              hipStream_t stream) {
    const float* img1 = (const float*)d_in[0];
    const float* img2 = (const float*)d_in[1];
    float* out = (float*)d_out;
    double* ws = (double*)d_ws;

    // d_ws is poisoned 0xAA before every launch — zero the accumulator (async, capture-safe)
    hipMemsetAsync(ws, 0, sizeof(double), stream);

    // Gaussian weights computed on host in double, passed via kernarg (SGPRs)
    GaussW gw;
    double g[TAPS], s = 0.0;
    for (int i = 0; i < TAPS; ++i) {
        double x = (double)(i - TAPS / 2);
        g[i] = exp(-(x * x) / (2.0 * 1.5 * 1.5));
        s += g[i];
    }
    for (int i = 0; i < TAPS; ++i) gw.w[i] = (float)(g[i] / s);

    // 2 x 16 x 48 = 1536 blocks; each block = 4 autonomous 64-col wave strips
    dim3 grid(IMG_W / (4 * STRIP), (IMG_H + CHUNK - 1) / CHUNK, NPLANES);
    ssim_main<<<grid, 256, 0, stream>>>(img1, img2, ws, gw);
    ssim_finalize<<<1, 1, 0, stream>>>(ws, out);
}